// Round 3
// baseline (332.125 us; speedup 1.0000x reference)
//
#include <hip/hip_runtime.h>
#include <math.h>

#define NN 4096
#define DD 512
#define F1 64
#define F2 32
#define F3 16
#define NH 4
#define ALPHA 0.2f
#define CAP 160   // max degree; Binomial(4096,0.01) mean 41, sigma 6.4 -> P(>160)~0

__device__ __forceinline__ float lrelu(float e) { return (e >= 0.f) ? e : ALPHA * e; }

// ---------------------------------------------------------------------------
// Kernel T: transpose W_heads [NH][DD][F1] -> Wt [NH][F1][DD]
// ---------------------------------------------------------------------------
__global__ void k_wtr(const float* __restrict__ W, float* __restrict__ Wt) {
  __shared__ float tile[64][65];
  int h = blockIdx.x >> 3;
  int kt = (blockIdx.x & 7) * 64;
  int tid = threadIdx.x;
  for (int t = tid; t < 4096; t += 256) {
    int kk = t >> 6, ff = t & 63;
    tile[kk][ff] = W[(size_t)h * DD * F1 + (size_t)(kt + kk) * F1 + ff];
  }
  __syncthreads();
  for (int t = tid; t < 4096; t += 256) {
    int ff = t >> 6, kk = t & 63;
    Wt[(size_t)(h * F1 + ff) * DD + kt + kk] = tile[kk][ff];
  }
}

// ---------------------------------------------------------------------------
// Kernel 0: build CSR from dense binary adj. One block per row, float4 scan.
// ---------------------------------------------------------------------------
__global__ void k_csr(const float* __restrict__ adj, int* __restrict__ colidx,
                      int* __restrict__ deg) {
  __shared__ int cnt;
  int i = blockIdx.x, tid = threadIdx.x;
  if (tid == 0) cnt = 0;
  __syncthreads();
  const float4* arow = (const float4*)(adj + (size_t)i * NN);
  for (int t = tid; t < NN / 4; t += 256) {
    float4 v = arow[t];
    int base = t * 4;
    if (v.x != 0.f) { int p = atomicAdd(&cnt, 1); if (p < CAP) colidx[(size_t)i * CAP + p] = base; }
    if (v.y != 0.f) { int p = atomicAdd(&cnt, 1); if (p < CAP) colidx[(size_t)i * CAP + p] = base + 1; }
    if (v.z != 0.f) { int p = atomicAdd(&cnt, 1); if (p < CAP) colidx[(size_t)i * CAP + p] = base + 2; }
    if (v.w != 0.f) { int p = atomicAdd(&cnt, 1); if (p < CAP) colidx[(size_t)i * CAP + p] = base + 3; }
  }
  __syncthreads();
  if (tid == 0) deg[i] = cnt < CAP ? cnt : CAP;
}

// ---------------------------------------------------------------------------
// Kernel 1: Whcat = x @ W (4 heads fused), s1/s2 logit reductions.
// 512 thr: f=tid&63, rg=(tid>>6)&3 (2 rows each), ks=tid>>8 (k-halves).
// Per 4-k: 2 LDS b128 (broadcast) + 4 global b128 (Wt) + 32 FMA -> ~65% VALU.
// ---------------------------------------------------------------------------
__global__ __launch_bounds__(512) void k_wh_heads(
    const float* __restrict__ x, const float* __restrict__ Wt,
    const float* __restrict__ a_heads, float* __restrict__ Whcat,
    float* __restrict__ s1, float* __restrict__ s2) {
  __shared__ float xs[8 * DD];  // 16 KB; reused as partial buffer
  int tid = threadIdx.x;
  int r0 = blockIdx.x * 8;
  const float4* xsrc = (const float4*)(x + (size_t)r0 * DD);
  float4* xd = (float4*)xs;
  xd[tid] = xsrc[tid];
  xd[tid + 512] = xsrc[tid + 512];
  __syncthreads();
  int f = tid & 63;
  int rg = (tid >> 6) & 3;
  int ks = tid >> 8;
  int k0 = ks * 256;
  const float* wp0 = Wt + (size_t)(0 * F1 + f) * DD;
  const float* wp1 = Wt + (size_t)(1 * F1 + f) * DD;
  const float* wp2 = Wt + (size_t)(2 * F1 + f) * DD;
  const float* wp3 = Wt + (size_t)(3 * F1 + f) * DD;
  const float* xa = xs + (size_t)(rg * 2) * DD;
  const float* xb = xa + DD;
  float acc[2][4] = {{0.f,0.f,0.f,0.f},{0.f,0.f,0.f,0.f}};
  for (int k = k0; k < k0 + 256; k += 4) {
    float4 wv[4];
    wv[0] = *(const float4*)(wp0 + k);
    wv[1] = *(const float4*)(wp1 + k);
    wv[2] = *(const float4*)(wp2 + k);
    wv[3] = *(const float4*)(wp3 + k);
    float4 va = *(const float4*)(xa + k);
    float4 vb = *(const float4*)(xb + k);
#pragma unroll
    for (int h = 0; h < 4; ++h) {
      acc[0][h] = fmaf(va.x, wv[h].x, acc[0][h]);
      acc[0][h] = fmaf(va.y, wv[h].y, acc[0][h]);
      acc[0][h] = fmaf(va.z, wv[h].z, acc[0][h]);
      acc[0][h] = fmaf(va.w, wv[h].w, acc[0][h]);
      acc[1][h] = fmaf(vb.x, wv[h].x, acc[1][h]);
      acc[1][h] = fmaf(vb.y, wv[h].y, acc[1][h]);
      acc[1][h] = fmaf(vb.z, wv[h].z, acc[1][h]);
      acc[1][h] = fmaf(vb.w, wv[h].w, acc[1][h]);
    }
  }
  __syncthreads();  // xs reads done; repurpose as partial buffer
  float* pbuf = xs;
  if (ks == 1) {
    int t = tid & 255;
#pragma unroll
    for (int r = 0; r < 2; ++r)
#pragma unroll
      for (int h = 0; h < 4; ++h) pbuf[t * 8 + r * 4 + h] = acc[r][h];
  }
  __syncthreads();
  if (ks == 0) {
#pragma unroll
    for (int r = 0; r < 2; ++r)
#pragma unroll
      for (int h = 0; h < 4; ++h) acc[r][h] += pbuf[tid * 8 + r * 4 + h];
    int rb = r0 + rg * 2;
#pragma unroll
    for (int r = 0; r < 2; ++r)
#pragma unroll
      for (int h = 0; h < 4; ++h)
        Whcat[(size_t)(rb + r) * (NH * F1) + h * 64 + f] = acc[r][h];
#pragma unroll
    for (int h = 0; h < 4; ++h) {
      float a1 = a_heads[h * 2 * F1 + f];
      float a2 = a_heads[h * 2 * F1 + F1 + f];
#pragma unroll
      for (int r = 0; r < 2; ++r) {
        float v1 = acc[r][h] * a1;
        float v2 = acc[r][h] * a2;
#pragma unroll
        for (int off = 32; off > 0; off >>= 1) {
          v1 += __shfl_down(v1, off, 64);
          v2 += __shfl_down(v2, off, 64);
        }
        if (f == 0) {
          s1[h * NN + rb + r] = v1;
          s2[h * NN + rb + r] = v2;
        }
      }
    }
  }
}

// ---------------------------------------------------------------------------
// Kernel 2: multi-head GAT aggregation. Block per row; wave h = head h.
// Weights precomputed in parallel; gather loop unrolled x4 (4 loads in flight).
// ---------------------------------------------------------------------------
__global__ void k_gat_heads(const int* __restrict__ colidx, const int* __restrict__ deg,
                            const float* __restrict__ Whcat,
                            const float* __restrict__ s1, const float* __restrict__ s2,
                            float* __restrict__ cat) {
  __shared__ int idx[CAP];
  __shared__ float wsh[NH][CAP];
  int i = blockIdx.x, tid = threadIdx.x;
  int c = deg[i];
  for (int t = tid; t < c; t += 256) idx[t] = colidx[(size_t)i * CAP + t];
  __syncthreads();
  int h = tid >> 6;
  int f = tid & 63;
  const float* s2h = s2 + h * NN;
  float s1v = s1[h * NN + i];
  float M = -INFINITY;
  for (int k = f; k < c; k += 64) {
    float v = s2h[idx[k]];
    wsh[h][k] = v;
    M = fmaxf(M, v);
  }
#pragma unroll
  for (int off = 32; off > 0; off >>= 1) M = fmaxf(M, __shfl_down(M, off, 64));
  M = __shfl(M, 0, 64);
  float m = lrelu(s1v + M);
  float lsum = 0.f;
  for (int k = f; k < c; k += 64) {
    float w = __expf(lrelu(s1v + wsh[h][k]) - m);
    wsh[h][k] = w;
    lsum += w;
  }
#pragma unroll
  for (int off = 32; off > 0; off >>= 1) lsum += __shfl_down(lsum, off, 64);
  float linv = 1.f / __shfl(lsum, 0, 64);
  __syncthreads();
  const float* base = Whcat + h * 64 + f;
  float a0 = 0.f, a1 = 0.f, a2 = 0.f, a3 = 0.f;
  int k = 0;
  for (; k + 4 <= c; k += 4) {
    int j0 = idx[k], j1 = idx[k + 1], j2 = idx[k + 2], j3 = idx[k + 3];
    a0 = fmaf(wsh[h][k],     base[(size_t)j0 * 256], a0);
    a1 = fmaf(wsh[h][k + 1], base[(size_t)j1 * 256], a1);
    a2 = fmaf(wsh[h][k + 2], base[(size_t)j2 * 256], a2);
    a3 = fmaf(wsh[h][k + 3], base[(size_t)j3 * 256], a3);
  }
  for (; k < c; ++k) a0 = fmaf(wsh[h][k], base[(size_t)idx[k] * 256], a0);
  float o = (a0 + a1 + a2 + a3) * linv;
  cat[(size_t)i * (NH * F1) + tid] = (o > 0.f) ? o : expm1f(o);
}

// ---------------------------------------------------------------------------
// Kernel 3: Wh2 = cat @ W_att  [NN,256]x[256,64], plus s1b/s2b reductions
// ---------------------------------------------------------------------------
__global__ void k_wh2(const float* __restrict__ cat,
                      const float* __restrict__ W_att,
                      const float* __restrict__ a_att,
                      float* __restrict__ Wh2,
                      float* __restrict__ s1b, float* __restrict__ s2b) {
  const int ROWS = 8;
  __shared__ float cs[ROWS][NH * F1];
  int tid = threadIdx.x;
  int r0 = blockIdx.x * ROWS;
  const float4* csrc = (const float4*)(cat + (size_t)r0 * 256);
  for (int t = tid; t < ROWS * 256 / 4; t += 256) ((float4*)cs)[t] = csrc[t];
  __syncthreads();
  int g = tid >> 6;
  int f = tid & 63;
  float a1 = a_att[f], a2 = a_att[64 + f];
  const float* W = W_att + f;
#pragma unroll
  for (int rr = 0; rr < 2; ++rr) {
    int r = g * 2 + rr;
    float acc = 0.f;
    for (int k = 0; k < 256; k += 4) {
      float4 cv = *(const float4*)&cs[r][k];
      acc = fmaf(cv.x, W[(k + 0) * 64], acc);
      acc = fmaf(cv.y, W[(k + 1) * 64], acc);
      acc = fmaf(cv.z, W[(k + 2) * 64], acc);
      acc = fmaf(cv.w, W[(k + 3) * 64], acc);
    }
    Wh2[(size_t)(r0 + r) * 64 + f] = acc;
    float v1 = acc * a1, v2 = acc * a2;
#pragma unroll
    for (int off = 32; off > 0; off >>= 1) {
      v1 += __shfl_down(v1, off, 64);
      v2 += __shfl_down(v2, off, 64);
    }
    if (f == 0) { s1b[r0 + r] = v1; s2b[r0 + r] = v2; }
  }
}

// ---------------------------------------------------------------------------
// Kernel 4: single-head GAT + fused t1 = gc @ W1. 4 rows/block, wave per row.
// gc never hits HBM.
// ---------------------------------------------------------------------------
__global__ void k_gat2t1(const int* __restrict__ colidx, const int* __restrict__ deg,
                         const float* __restrict__ Wh2,
                         const float* __restrict__ s1b, const float* __restrict__ s2b,
                         const float* __restrict__ W1, float* __restrict__ t1) {
  __shared__ int idx4[4][CAP];
  __shared__ float wsh4[4][CAP];
  __shared__ float grow[4][64];
  __shared__ float W1s[F1 * F2];  // 8 KB
  int tid = threadIdx.x;
  int w = tid >> 6, f = tid & 63;
  int i = blockIdx.x * 4 + w;
  int c = deg[i];
  for (int t = tid; t < F1 * F2; t += 256) W1s[t] = W1[t];
  for (int k = f; k < c; k += 64) idx4[w][k] = colidx[(size_t)i * CAP + k];
  __syncthreads();
  float s1v = s1b[i];
  float M = -INFINITY;
  for (int k = f; k < c; k += 64) {
    float v = s2b[idx4[w][k]];
    wsh4[w][k] = v;
    M = fmaxf(M, v);
  }
#pragma unroll
  for (int off = 32; off > 0; off >>= 1) M = fmaxf(M, __shfl_down(M, off, 64));
  M = __shfl(M, 0, 64);
  float m = lrelu(s1v + M);
  float lsum = 0.f;
  for (int k = f; k < c; k += 64) {
    float wv = __expf(lrelu(s1v + wsh4[w][k]) - m);
    wsh4[w][k] = wv;
    lsum += wv;
  }
#pragma unroll
  for (int off = 32; off > 0; off >>= 1) lsum += __shfl_down(lsum, off, 64);
  float linv = 1.f / __shfl(lsum, 0, 64);
  __syncthreads();
  const float* base = Wh2 + f;
  float a0 = 0.f, a1 = 0.f, a2 = 0.f, a3 = 0.f;
  int k = 0;
  for (; k + 4 <= c; k += 4) {
    int j0 = idx4[w][k], j1 = idx4[w][k + 1], j2 = idx4[w][k + 2], j3 = idx4[w][k + 3];
    a0 = fmaf(wsh4[w][k],     base[(size_t)j0 * 64], a0);
    a1 = fmaf(wsh4[w][k + 1], base[(size_t)j1 * 64], a1);
    a2 = fmaf(wsh4[w][k + 2], base[(size_t)j2 * 64], a2);
    a3 = fmaf(wsh4[w][k + 3], base[(size_t)j3 * 64], a3);
  }
  for (; k < c; ++k) a0 = fmaf(wsh4[w][k], base[(size_t)idx4[w][k] * 64], a0);
  float o = (a0 + a1 + a2 + a3) * linv;
  grow[w][f] = (o > 0.f) ? o : expm1f(o);
  __syncthreads();
  if (f < F2) {
    float acc = 0.f;
#pragma unroll 8
    for (int kk = 0; kk < F1; ++kk) acc = fmaf(grow[w][kk], W1s[kk * F2 + f], acc);
    t1[(size_t)i * F2 + f] = acc;
  }
}

// ---------------------------------------------------------------------------
// Kernel 5: h1 = relu(adj @ t1) fused with t23 = h1 @ [W2|W3].
// 4 rows/block, wave per row, 2 neighbors per iter (64 lanes = 2 x 32 feats).
// h1 never hits HBM.
// ---------------------------------------------------------------------------
__global__ void k_gcn1t23(const int* __restrict__ colidx, const int* __restrict__ deg,
                          const float* __restrict__ t1,
                          const float* __restrict__ W2, const float* __restrict__ W3,
                          float* __restrict__ t23) {
  __shared__ int idx4[4][CAP];
  __shared__ float hrow[4][F2];
  __shared__ float Wc[F2 * 32];  // [k][g]: g<16 -> W2, g>=16 -> W3
  int tid = threadIdx.x;
  int w = tid >> 6, lane = tid & 63;
  int nb = lane >> 5, g = lane & 31;
  int i = blockIdx.x * 4 + w;
  int c = deg[i];
  for (int t = tid; t < F2 * 32; t += 256) {
    int kk = t >> 5, gg = t & 31;
    Wc[t] = (gg < 16) ? W2[kk * 16 + gg] : W3[kk * 16 + (gg - 16)];
  }
  for (int k = lane; k < c; k += 64) idx4[w][k] = colidx[(size_t)i * CAP + k];
  __syncthreads();
  float a0 = 0.f, a1 = 0.f;
  int k = nb;
  for (; k + 2 < c; k += 4) {
    a0 += t1[(size_t)idx4[w][k] * F2 + g];
    a1 += t1[(size_t)idx4[w][k + 2] * F2 + g];
  }
  for (; k < c; k += 2) a0 += t1[(size_t)idx4[w][k] * F2 + g];
  float tot = a0 + a1;
  tot += __shfl_xor(tot, 32, 64);
  float h1v = fmaxf(tot, 0.f);
  if (nb == 0) hrow[w][g] = h1v;
  __syncthreads();
  if (lane < 32) {
    float acc = 0.f;
#pragma unroll 8
    for (int kk = 0; kk < F2; ++kk) acc = fmaf(hrow[w][kk], Wc[kk * 32 + lane], acc);
    t23[(size_t)i * 32 + lane] = acc;
  }
}

// ---------------------------------------------------------------------------
// Kernel 6: mu/logvar = adj @ t23 ; z = eps*exp(logvar)+mu. Wave per row.
// ---------------------------------------------------------------------------
__global__ void k_gcn2(const int* __restrict__ colidx, const int* __restrict__ deg,
                       const float* __restrict__ t23, const float* __restrict__ eps,
                       float* __restrict__ mu_out, float* __restrict__ lv_out,
                       float* __restrict__ z) {
  __shared__ int idx4[4][CAP];
  int tid = threadIdx.x;
  int w = tid >> 6, lane = tid & 63;
  int nb = lane >> 5, g = lane & 31;
  int i = blockIdx.x * 4 + w;
  int c = deg[i];
  for (int k = lane; k < c; k += 64) idx4[w][k] = colidx[(size_t)i * CAP + k];
  __syncthreads();
  float a0 = 0.f, a1 = 0.f;
  int k = nb;
  for (; k + 2 < c; k += 4) {
    a0 += t23[(size_t)idx4[w][k] * 32 + g];
    a1 += t23[(size_t)idx4[w][k + 2] * 32 + g];
  }
  for (; k < c; k += 2) a0 += t23[(size_t)idx4[w][k] * 32 + g];
  float tot = a0 + a1;
  tot += __shfl_xor(tot, 32, 64);
  // lanes 0..31 hold [mu(0..15) | lv(16..31)]
  float lvv = __shfl(tot, (lane & 31) + 16, 64);  // valid for g<16
  if (lane < 16) {
    mu_out[(size_t)i * 16 + g] = tot;
    z[(size_t)i * 16 + g] = eps[(size_t)i * 16 + g] * expf(lvv) + tot;
  } else if (lane < 32) {
    lv_out[(size_t)i * 16 + (g - 16)] = tot;
  }
}

// ---------------------------------------------------------------------------
// Kernel 7: adj_rec = z @ z^T. 64x64 tiles, rank-16, float4 stores.
// ---------------------------------------------------------------------------
__global__ void k_zzt(const float* __restrict__ z, float* __restrict__ out) {
  __shared__ float zr[64][17];
  __shared__ float zc[64][17];
  int bj = blockIdx.x, bi = blockIdx.y;
  int tid = threadIdx.x;
  for (int t = tid; t < 64 * 16; t += 256) {
    int r = t >> 4, kk = t & 15;
    zr[r][kk] = z[(size_t)(bi * 64 + r) * 16 + kk];
    zc[r][kk] = z[(size_t)(bj * 64 + r) * 16 + kk];
  }
  __syncthreads();
  int rg = tid >> 4;        // 16 row groups x 4 rows
  int cg = tid & 15;        // 16 col groups x 4 cols
  float acc[4][4] = {};
  for (int kk = 0; kk < 16; ++kk) {
    float av[4], bv[4];
#pragma unroll
    for (int t = 0; t < 4; ++t) av[t] = zr[rg * 4 + t][kk];
#pragma unroll
    for (int t = 0; t < 4; ++t) bv[t] = zc[cg * 4 + t][kk];
#pragma unroll
    for (int r = 0; r < 4; ++r)
#pragma unroll
      for (int cc = 0; cc < 4; ++cc) acc[r][cc] = fmaf(av[r], bv[cc], acc[r][cc]);
  }
#pragma unroll
  for (int r = 0; r < 4; ++r) {
    float4 v = make_float4(acc[r][0], acc[r][1], acc[r][2], acc[r][3]);
    *(float4*)&out[(size_t)(bi * 64 + rg * 4 + r) * NN + bj * 64 + cg * 4] = v;
  }
}

extern "C" void kernel_launch(void* const* d_in, const int* in_sizes, int n_in,
                              void* d_out, int out_size, void* d_ws, size_t ws_size,
                              hipStream_t stream) {
  const float* x       = (const float*)d_in[0];
  const float* adj     = (const float*)d_in[1];
  const float* W_heads = (const float*)d_in[2];
  const float* a_heads = (const float*)d_in[3];
  const float* W_att   = (const float*)d_in[4];
  const float* a_att   = (const float*)d_in[5];
  const float* W1      = (const float*)d_in[6];
  const float* W2      = (const float*)d_in[7];
  const float* W3      = (const float*)d_in[8];
  const float* eps     = (const float*)d_in[9];

  float* out = (float*)d_out;
  float* adj_rec = out;
  float* mu_out  = out + (size_t)NN * NN;
  float* lv_out  = mu_out + (size_t)NN * F3;

  float* ws = (float*)d_ws;
  float* Whcat = ws;               ws += (size_t)NN * NH * F1;
  float* s1    = ws;               ws += (size_t)NH * NN;
  float* s2    = ws;               ws += (size_t)NH * NN;
  float* cat   = ws;               ws += (size_t)NN * NH * F1;
  float* Wh2   = ws;               ws += (size_t)NN * F1;
  float* s1b   = ws;               ws += NN;
  float* s2b   = ws;               ws += NN;
  float* t1    = ws;               ws += (size_t)NN * F2;
  float* t23   = ws;               ws += (size_t)NN * 2 * F3;
  float* z     = ws;               ws += (size_t)NN * F3;
  float* Wt    = ws;               ws += (size_t)NH * F1 * DD;
  int*   colidx = (int*)ws;        ws += (size_t)NN * CAP;
  int*   deg    = (int*)ws;        ws += NN;

  k_wtr<<<32, 256, 0, stream>>>(W_heads, Wt);
  k_csr<<<NN, 256, 0, stream>>>(adj, colidx, deg);
  k_wh_heads<<<NN / 8, 512, 0, stream>>>(x, Wt, a_heads, Whcat, s1, s2);
  k_gat_heads<<<NN, 256, 0, stream>>>(colidx, deg, Whcat, s1, s2, cat);
  k_wh2<<<NN / 8, 256, 0, stream>>>(cat, W_att, a_att, Wh2, s1b, s2b);
  k_gat2t1<<<NN / 4, 256, 0, stream>>>(colidx, deg, Wh2, s1b, s2b, W1, t1);
  k_gcn1t23<<<NN / 4, 256, 0, stream>>>(colidx, deg, t1, W2, W3, t23);
  k_gcn2<<<NN / 4, 256, 0, stream>>>(colidx, deg, t23, eps, mu_out, lv_out, z);
  k_zzt<<<dim3(64, 64), 256, 0, stream>>>(z, adj_rec);
}

// Round 4
// 237.228 us; speedup vs baseline: 1.4000x; 1.4000x over previous
//
#include <hip/hip_runtime.h>
#include <math.h>

#define NN 4096
#define DD 512
#define F1 64
#define F2 32
#define F3 16
#define NH 4
#define ALPHA 0.2f
#define CAP 160   // max degree; Binomial(4096,0.01) mean 41, sigma 6.4 -> P(>160)~0

__device__ __forceinline__ float lrelu(float e) { return (e >= 0.f) ? e : ALPHA * e; }

// ---------------------------------------------------------------------------
// Kernel 0: build CSR from dense binary adj. One block per row, float4 scan.
// ---------------------------------------------------------------------------
__global__ void k_csr(const float* __restrict__ adj, int* __restrict__ colidx,
                      int* __restrict__ deg) {
  __shared__ int cnt;
  int i = blockIdx.x, tid = threadIdx.x;
  if (tid == 0) cnt = 0;
  __syncthreads();
  const float4* arow = (const float4*)(adj + (size_t)i * NN);
  for (int t = tid; t < NN / 4; t += 256) {
    float4 v = arow[t];
    int base = t * 4;
    if (v.x != 0.f) { int p = atomicAdd(&cnt, 1); if (p < CAP) colidx[(size_t)i * CAP + p] = base; }
    if (v.y != 0.f) { int p = atomicAdd(&cnt, 1); if (p < CAP) colidx[(size_t)i * CAP + p] = base + 1; }
    if (v.z != 0.f) { int p = atomicAdd(&cnt, 1); if (p < CAP) colidx[(size_t)i * CAP + p] = base + 2; }
    if (v.w != 0.f) { int p = atomicAdd(&cnt, 1); if (p < CAP) colidx[(size_t)i * CAP + p] = base + 3; }
  }
  __syncthreads();
  if (tid == 0) deg[i] = cnt < CAP ? cnt : CAP;
}

// ---------------------------------------------------------------------------
// Kernel 1: Whcat = x @ W_heads (4 heads fused per thread), s1/s2 reductions.
// 256 thr / 8 rows / 512 blocks. Wave w: row-group w>>1 (4 rows), k-half w&1.
// Per k-group of 4: 16 coalesced W loads (W[h][k][f], lane=f -> 256B lines,
// L2-hot) + 4 ds_read_b128 (broadcast) + 64 FMA  =>  ~76% FMA issue mix.
// ---------------------------------------------------------------------------
__global__ __launch_bounds__(256) void k_wh_heads(
    const float* __restrict__ x, const float* __restrict__ W_heads,
    const float* __restrict__ a_heads, float* __restrict__ Whcat,
    float* __restrict__ s1, float* __restrict__ s2) {
  __shared__ float xs[8][DD];            // 16 KB
  __shared__ float pbuf[2][4][4][64];    // [rowgrp][r][h][f] partials, 8 KB
  int tid = threadIdx.x;
  int r0 = blockIdx.x * 8;
  const float4* xsrc = (const float4*)(x + (size_t)r0 * DD);
  float4* xd = (float4*)xs;
  xd[tid] = xsrc[tid];
  xd[tid + 256] = xsrc[tid + 256];
  xd[tid + 512] = xsrc[tid + 512];
  xd[tid + 768] = xsrc[tid + 768];
  __syncthreads();
  int f = tid & 63;
  int w = tid >> 6;
  int rg = w >> 1;        // row group: rows rg*4 .. rg*4+3
  int kh = w & 1;         // k half
  int k0 = kh * 256;
  const float* Wf = W_heads + f;
  float acc[4][4] = {};   // [r][h]
  for (int k = k0; k < k0 + 256; k += 4) {
    float wv[4][4];       // [h][kk]
#pragma unroll
    for (int h = 0; h < 4; ++h)
#pragma unroll
      for (int kk = 0; kk < 4; ++kk)
        wv[h][kk] = Wf[(size_t)h * DD * F1 + (size_t)(k + kk) * F1];
    float4 xv[4];
#pragma unroll
    for (int r = 0; r < 4; ++r) xv[r] = *(const float4*)&xs[rg * 4 + r][k];
#pragma unroll
    for (int r = 0; r < 4; ++r)
#pragma unroll
      for (int h = 0; h < 4; ++h) {
        acc[r][h] = fmaf(xv[r].x, wv[h][0], acc[r][h]);
        acc[r][h] = fmaf(xv[r].y, wv[h][1], acc[r][h]);
        acc[r][h] = fmaf(xv[r].z, wv[h][2], acc[r][h]);
        acc[r][h] = fmaf(xv[r].w, wv[h][3], acc[r][h]);
      }
  }
  // combine the two k-halves through LDS; even waves (kh==0) finish.
  if (kh == 1) {
#pragma unroll
    for (int r = 0; r < 4; ++r)
#pragma unroll
      for (int h = 0; h < 4; ++h) pbuf[rg][r][h][f] = acc[r][h];
  }
  __syncthreads();
  if (kh == 0) {
#pragma unroll
    for (int r = 0; r < 4; ++r)
#pragma unroll
      for (int h = 0; h < 4; ++h) acc[r][h] += pbuf[rg][r][h][f];
    int rb = r0 + rg * 4;
#pragma unroll
    for (int r = 0; r < 4; ++r)
#pragma unroll
      for (int h = 0; h < 4; ++h)
        Whcat[(size_t)(rb + r) * (NH * F1) + h * 64 + f] = acc[r][h];
#pragma unroll
    for (int h = 0; h < 4; ++h) {
      float a1 = a_heads[h * 2 * F1 + f];
      float a2 = a_heads[h * 2 * F1 + F1 + f];
#pragma unroll
      for (int r = 0; r < 4; ++r) {
        float v1 = acc[r][h] * a1;
        float v2 = acc[r][h] * a2;
#pragma unroll
        for (int off = 32; off > 0; off >>= 1) {
          v1 += __shfl_down(v1, off, 64);
          v2 += __shfl_down(v2, off, 64);
        }
        if (f == 0) {
          s1[h * NN + rb + r] = v1;
          s2[h * NN + rb + r] = v2;
        }
      }
    }
  }
}

// ---------------------------------------------------------------------------
// Kernel 2: multi-head GAT aggregation. Block per row; wave h = head h.
// Weights precomputed in parallel; gather loop unrolled x4 (4 loads in flight).
// ---------------------------------------------------------------------------
__global__ void k_gat_heads(const int* __restrict__ colidx, const int* __restrict__ deg,
                            const float* __restrict__ Whcat,
                            const float* __restrict__ s1, const float* __restrict__ s2,
                            float* __restrict__ cat) {
  __shared__ int idx[CAP];
  __shared__ float wsh[NH][CAP];
  int i = blockIdx.x, tid = threadIdx.x;
  int c = deg[i];
  for (int t = tid; t < c; t += 256) idx[t] = colidx[(size_t)i * CAP + t];
  __syncthreads();
  int h = tid >> 6;
  int f = tid & 63;
  const float* s2h = s2 + h * NN;
  float s1v = s1[h * NN + i];
  float M = -INFINITY;
  for (int k = f; k < c; k += 64) {
    float v = s2h[idx[k]];
    wsh[h][k] = v;
    M = fmaxf(M, v);
  }
#pragma unroll
  for (int off = 32; off > 0; off >>= 1) M = fmaxf(M, __shfl_down(M, off, 64));
  M = __shfl(M, 0, 64);
  float m = lrelu(s1v + M);
  float lsum = 0.f;
  for (int k = f; k < c; k += 64) {
    float w = __expf(lrelu(s1v + wsh[h][k]) - m);
    wsh[h][k] = w;
    lsum += w;
  }
#pragma unroll
  for (int off = 32; off > 0; off >>= 1) lsum += __shfl_down(lsum, off, 64);
  float linv = 1.f / __shfl(lsum, 0, 64);
  __syncthreads();
  const float* base = Whcat + h * 64 + f;
  float a0 = 0.f, a1 = 0.f, a2 = 0.f, a3 = 0.f;
  int k = 0;
  for (; k + 4 <= c; k += 4) {
    int j0 = idx[k], j1 = idx[k + 1], j2 = idx[k + 2], j3 = idx[k + 3];
    a0 = fmaf(wsh[h][k],     base[(size_t)j0 * 256], a0);
    a1 = fmaf(wsh[h][k + 1], base[(size_t)j1 * 256], a1);
    a2 = fmaf(wsh[h][k + 2], base[(size_t)j2 * 256], a2);
    a3 = fmaf(wsh[h][k + 3], base[(size_t)j3 * 256], a3);
  }
  for (; k < c; ++k) a0 = fmaf(wsh[h][k], base[(size_t)idx[k] * 256], a0);
  float o = (a0 + a1 + a2 + a3) * linv;
  cat[(size_t)i * (NH * F1) + tid] = (o > 0.f) ? o : expm1f(o);
}

// ---------------------------------------------------------------------------
// Kernel 3: Wh2 = cat @ W_att  [NN,256]x[256,64], plus s1b/s2b reductions
// ---------------------------------------------------------------------------
__global__ void k_wh2(const float* __restrict__ cat,
                      const float* __restrict__ W_att,
                      const float* __restrict__ a_att,
                      float* __restrict__ Wh2,
                      float* __restrict__ s1b, float* __restrict__ s2b) {
  const int ROWS = 8;
  __shared__ float cs[ROWS][NH * F1];
  int tid = threadIdx.x;
  int r0 = blockIdx.x * ROWS;
  const float4* csrc = (const float4*)(cat + (size_t)r0 * 256);
  for (int t = tid; t < ROWS * 256 / 4; t += 256) ((float4*)cs)[t] = csrc[t];
  __syncthreads();
  int g = tid >> 6;
  int f = tid & 63;
  float a1 = a_att[f], a2 = a_att[64 + f];
  const float* W = W_att + f;
#pragma unroll
  for (int rr = 0; rr < 2; ++rr) {
    int r = g * 2 + rr;
    float acc = 0.f;
    for (int k = 0; k < 256; k += 4) {
      float4 cv = *(const float4*)&cs[r][k];
      acc = fmaf(cv.x, W[(k + 0) * 64], acc);
      acc = fmaf(cv.y, W[(k + 1) * 64], acc);
      acc = fmaf(cv.z, W[(k + 2) * 64], acc);
      acc = fmaf(cv.w, W[(k + 3) * 64], acc);
    }
    Wh2[(size_t)(r0 + r) * 64 + f] = acc;
    float v1 = acc * a1, v2 = acc * a2;
#pragma unroll
    for (int off = 32; off > 0; off >>= 1) {
      v1 += __shfl_down(v1, off, 64);
      v2 += __shfl_down(v2, off, 64);
    }
    if (f == 0) { s1b[r0 + r] = v1; s2b[r0 + r] = v2; }
  }
}

// ---------------------------------------------------------------------------
// Kernel 4: single-head GAT + fused t1 = gc @ W1. 4 rows/block, wave per row.
// gc never hits HBM.
// ---------------------------------------------------------------------------
__global__ void k_gat2t1(const int* __restrict__ colidx, const int* __restrict__ deg,
                         const float* __restrict__ Wh2,
                         const float* __restrict__ s1b, const float* __restrict__ s2b,
                         const float* __restrict__ W1, float* __restrict__ t1) {
  __shared__ int idx4[4][CAP];
  __shared__ float wsh4[4][CAP];
  __shared__ float grow[4][64];
  __shared__ float W1s[F1 * F2];  // 8 KB
  int tid = threadIdx.x;
  int w = tid >> 6, f = tid & 63;
  int i = blockIdx.x * 4 + w;
  int c = deg[i];
  for (int t = tid; t < F1 * F2; t += 256) W1s[t] = W1[t];
  for (int k = f; k < c; k += 64) idx4[w][k] = colidx[(size_t)i * CAP + k];
  __syncthreads();
  float s1v = s1b[i];
  float M = -INFINITY;
  for (int k = f; k < c; k += 64) {
    float v = s2b[idx4[w][k]];
    wsh4[w][k] = v;
    M = fmaxf(M, v);
  }
#pragma unroll
  for (int off = 32; off > 0; off >>= 1) M = fmaxf(M, __shfl_down(M, off, 64));
  M = __shfl(M, 0, 64);
  float m = lrelu(s1v + M);
  float lsum = 0.f;
  for (int k = f; k < c; k += 64) {
    float wv = __expf(lrelu(s1v + wsh4[w][k]) - m);
    wsh4[w][k] = wv;
    lsum += wv;
  }
#pragma unroll
  for (int off = 32; off > 0; off >>= 1) lsum += __shfl_down(lsum, off, 64);
  float linv = 1.f / __shfl(lsum, 0, 64);
  __syncthreads();
  const float* base = Wh2 + f;
  float a0 = 0.f, a1 = 0.f, a2 = 0.f, a3 = 0.f;
  int k = 0;
  for (; k + 4 <= c; k += 4) {
    int j0 = idx4[w][k], j1 = idx4[w][k + 1], j2 = idx4[w][k + 2], j3 = idx4[w][k + 3];
    a0 = fmaf(wsh4[w][k],     base[(size_t)j0 * 64], a0);
    a1 = fmaf(wsh4[w][k + 1], base[(size_t)j1 * 64], a1);
    a2 = fmaf(wsh4[w][k + 2], base[(size_t)j2 * 64], a2);
    a3 = fmaf(wsh4[w][k + 3], base[(size_t)j3 * 64], a3);
  }
  for (; k < c; ++k) a0 = fmaf(wsh4[w][k], base[(size_t)idx4[w][k] * 64], a0);
  float o = (a0 + a1 + a2 + a3) * linv;
  grow[w][f] = (o > 0.f) ? o : expm1f(o);
  __syncthreads();
  if (f < F2) {
    float acc = 0.f;
#pragma unroll 8
    for (int kk = 0; kk < F1; ++kk) acc = fmaf(grow[w][kk], W1s[kk * F2 + f], acc);
    t1[(size_t)i * F2 + f] = acc;
  }
}

// ---------------------------------------------------------------------------
// Kernel 5: h1 = relu(adj @ t1) fused with t23 = h1 @ [W2|W3].
// 4 rows/block, wave per row, 2 neighbors per iter (64 lanes = 2 x 32 feats).
// h1 never hits HBM.
// ---------------------------------------------------------------------------
__global__ void k_gcn1t23(const int* __restrict__ colidx, const int* __restrict__ deg,
                          const float* __restrict__ t1,
                          const float* __restrict__ W2, const float* __restrict__ W3,
                          float* __restrict__ t23) {
  __shared__ int idx4[4][CAP];
  __shared__ float hrow[4][F2];
  __shared__ float Wc[F2 * 32];  // [k][g]: g<16 -> W2, g>=16 -> W3
  int tid = threadIdx.x;
  int w = tid >> 6, lane = tid & 63;
  int nb = lane >> 5, g = lane & 31;
  int i = blockIdx.x * 4 + w;
  int c = deg[i];
  for (int t = tid; t < F2 * 32; t += 256) {
    int kk = t >> 5, gg = t & 31;
    Wc[t] = (gg < 16) ? W2[kk * 16 + gg] : W3[kk * 16 + (gg - 16)];
  }
  for (int k = lane; k < c; k += 64) idx4[w][k] = colidx[(size_t)i * CAP + k];
  __syncthreads();
  float a0 = 0.f, a1 = 0.f;
  int k = nb;
  for (; k + 2 < c; k += 4) {
    a0 += t1[(size_t)idx4[w][k] * F2 + g];
    a1 += t1[(size_t)idx4[w][k + 2] * F2 + g];
  }
  for (; k < c; k += 2) a0 += t1[(size_t)idx4[w][k] * F2 + g];
  float tot = a0 + a1;
  tot += __shfl_xor(tot, 32, 64);
  float h1v = fmaxf(tot, 0.f);
  if (nb == 0) hrow[w][g] = h1v;
  __syncthreads();
  if (lane < 32) {
    float acc = 0.f;
#pragma unroll 8
    for (int kk = 0; kk < F2; ++kk) acc = fmaf(hrow[w][kk], Wc[kk * 32 + lane], acc);
    t23[(size_t)i * 32 + lane] = acc;
  }
}

// ---------------------------------------------------------------------------
// Kernel 6: mu/logvar = adj @ t23 ; z = eps*exp(logvar)+mu. Wave per row.
// ---------------------------------------------------------------------------
__global__ void k_gcn2(const int* __restrict__ colidx, const int* __restrict__ deg,
                       const float* __restrict__ t23, const float* __restrict__ eps,
                       float* __restrict__ mu_out, float* __restrict__ lv_out,
                       float* __restrict__ z) {
  __shared__ int idx4[4][CAP];
  int tid = threadIdx.x;
  int w = tid >> 6, lane = tid & 63;
  int nb = lane >> 5, g = lane & 31;
  int i = blockIdx.x * 4 + w;
  int c = deg[i];
  for (int k = lane; k < c; k += 64) idx4[w][k] = colidx[(size_t)i * CAP + k];
  __syncthreads();
  float a0 = 0.f, a1 = 0.f;
  int k = nb;
  for (; k + 2 < c; k += 4) {
    a0 += t23[(size_t)idx4[w][k] * 32 + g];
    a1 += t23[(size_t)idx4[w][k + 2] * 32 + g];
  }
  for (; k < c; k += 2) a0 += t23[(size_t)idx4[w][k] * 32 + g];
  float tot = a0 + a1;
  tot += __shfl_xor(tot, 32, 64);
  // lanes 0..31 hold [mu(0..15) | lv(16..31)]
  float lvv = __shfl(tot, (lane & 31) + 16, 64);  // valid for g<16
  if (lane < 16) {
    mu_out[(size_t)i * 16 + g] = tot;
    z[(size_t)i * 16 + g] = eps[(size_t)i * 16 + g] * expf(lvv) + tot;
  } else if (lane < 32) {
    lv_out[(size_t)i * 16 + (g - 16)] = tot;
  }
}

// ---------------------------------------------------------------------------
// Kernel 7: adj_rec = z @ z^T. 64x64 tiles, rank-16, float4 stores.
// ---------------------------------------------------------------------------
__global__ void k_zzt(const float* __restrict__ z, float* __restrict__ out) {
  __shared__ float zr[64][17];
  __shared__ float zc[64][17];
  int bj = blockIdx.x, bi = blockIdx.y;
  int tid = threadIdx.x;
  for (int t = tid; t < 64 * 16; t += 256) {
    int r = t >> 4, kk = t & 15;
    zr[r][kk] = z[(size_t)(bi * 64 + r) * 16 + kk];
    zc[r][kk] = z[(size_t)(bj * 64 + r) * 16 + kk];
  }
  __syncthreads();
  int rg = tid >> 4;        // 16 row groups x 4 rows
  int cg = tid & 15;        // 16 col groups x 4 cols
  float acc[4][4] = {};
  for (int kk = 0; kk < 16; ++kk) {
    float av[4], bv[4];
#pragma unroll
    for (int t = 0; t < 4; ++t) av[t] = zr[rg * 4 + t][kk];
#pragma unroll
    for (int t = 0; t < 4; ++t) bv[t] = zc[cg * 4 + t][kk];
#pragma unroll
    for (int r = 0; r < 4; ++r)
#pragma unroll
      for (int cc = 0; cc < 4; ++cc) acc[r][cc] = fmaf(av[r], bv[cc], acc[r][cc]);
  }
#pragma unroll
  for (int r = 0; r < 4; ++r) {
    float4 v = make_float4(acc[r][0], acc[r][1], acc[r][2], acc[r][3]);
    *(float4*)&out[(size_t)(bi * 64 + rg * 4 + r) * NN + bj * 64 + cg * 4] = v;
  }
}

extern "C" void kernel_launch(void* const* d_in, const int* in_sizes, int n_in,
                              void* d_out, int out_size, void* d_ws, size_t ws_size,
                              hipStream_t stream) {
  const float* x       = (const float*)d_in[0];
  const float* adj     = (const float*)d_in[1];
  const float* W_heads = (const float*)d_in[2];
  const float* a_heads = (const float*)d_in[3];
  const float* W_att   = (const float*)d_in[4];
  const float* a_att   = (const float*)d_in[5];
  const float* W1      = (const float*)d_in[6];
  const float* W2      = (const float*)d_in[7];
  const float* W3      = (const float*)d_in[8];
  const float* eps     = (const float*)d_in[9];

  float* out = (float*)d_out;
  float* adj_rec = out;
  float* mu_out  = out + (size_t)NN * NN;
  float* lv_out  = mu_out + (size_t)NN * F3;

  float* ws = (float*)d_ws;
  float* Whcat = ws;               ws += (size_t)NN * NH * F1;
  float* s1    = ws;               ws += (size_t)NH * NN;
  float* s2    = ws;               ws += (size_t)NH * NN;
  float* cat   = ws;               ws += (size_t)NN * NH * F1;
  float* Wh2   = ws;               ws += (size_t)NN * F1;
  float* s1b   = ws;               ws += NN;
  float* s2b   = ws;               ws += NN;
  float* t1    = ws;               ws += (size_t)NN * F2;
  float* t23   = ws;               ws += (size_t)NN * 2 * F3;
  float* z     = ws;               ws += (size_t)NN * F3;
  int*   colidx = (int*)ws;        ws += (size_t)NN * CAP;
  int*   deg    = (int*)ws;        ws += NN;

  k_csr<<<NN, 256, 0, stream>>>(adj, colidx, deg);
  k_wh_heads<<<NN / 8, 256, 0, stream>>>(x, W_heads, a_heads, Whcat, s1, s2);
  k_gat_heads<<<NN, 256, 0, stream>>>(colidx, deg, Whcat, s1, s2, cat);
  k_wh2<<<NN / 8, 256, 0, stream>>>(cat, W_att, a_att, Wh2, s1b, s2b);
  k_gat2t1<<<NN / 4, 256, 0, stream>>>(colidx, deg, Wh2, s1b, s2b, W1, t1);
  k_gcn1t23<<<NN / 4, 256, 0, stream>>>(colidx, deg, t1, W2, W3, t23);
  k_gcn2<<<NN / 4, 256, 0, stream>>>(colidx, deg, t23, eps, mu_out, lv_out, z);
  k_zzt<<<dim3(64, 64), 256, 0, stream>>>(z, adj_rec);
}

// Round 5
// 229.772 us; speedup vs baseline: 1.4455x; 1.0324x over previous
//
#include <hip/hip_runtime.h>
#include <math.h>

#define NN 4096
#define DD 512
#define F1 64
#define F2 32
#define F3 16
#define NH 4
#define ALPHA 0.2f
#define CAP 160   // max degree; Binomial(4096,0.01) mean 41, sigma 6.4 -> P(>160)~0

__device__ __forceinline__ float lrelu(float e) { return (e >= 0.f) ? e : ALPHA * e; }

// ---------------------------------------------------------------------------
// Kernel 0: build CSR from dense binary adj. One block per row, float4 scan.
// ---------------------------------------------------------------------------
__global__ void k_csr(const float* __restrict__ adj, int* __restrict__ colidx,
                      int* __restrict__ deg) {
  __shared__ int cnt;
  int i = blockIdx.x, tid = threadIdx.x;
  if (tid == 0) cnt = 0;
  __syncthreads();
  const float4* arow = (const float4*)(adj + (size_t)i * NN);
  for (int t = tid; t < NN / 4; t += 256) {
    float4 v = arow[t];
    int base = t * 4;
    if (v.x != 0.f) { int p = atomicAdd(&cnt, 1); if (p < CAP) colidx[(size_t)i * CAP + p] = base; }
    if (v.y != 0.f) { int p = atomicAdd(&cnt, 1); if (p < CAP) colidx[(size_t)i * CAP + p] = base + 1; }
    if (v.z != 0.f) { int p = atomicAdd(&cnt, 1); if (p < CAP) colidx[(size_t)i * CAP + p] = base + 2; }
    if (v.w != 0.f) { int p = atomicAdd(&cnt, 1); if (p < CAP) colidx[(size_t)i * CAP + p] = base + 3; }
  }
  __syncthreads();
  if (tid == 0) deg[i] = cnt < CAP ? cnt : CAP;
}

// ---------------------------------------------------------------------------
// Kernel 1 helpers: load one k-group of 8 (32 W values + 8 x float4s) and the
// matching 128 FMAs. Statically indexed so everything stays in registers.
// ---------------------------------------------------------------------------
__device__ __forceinline__ void wh_load(const float* __restrict__ Wf,
                                        const float xsrow[8][DD], int rg, int g,
                                        float* w, float4* xv) {
#pragma unroll
  for (int h = 0; h < 4; ++h)
#pragma unroll
    for (int kk = 0; kk < 8; ++kk)
      w[h * 8 + kk] = Wf[(size_t)h * DD * F1 + (size_t)(g + kk) * F1];
#pragma unroll
  for (int r = 0; r < 4; ++r) {
    xv[r * 2 + 0] = *(const float4*)&xsrow[rg * 4 + r][g];
    xv[r * 2 + 1] = *(const float4*)&xsrow[rg * 4 + r][g + 4];
  }
}

__device__ __forceinline__ void wh_fma(const float* w, const float4* xv,
                                       float acc[4][4]) {
#pragma unroll
  for (int r = 0; r < 4; ++r) {
    float4 a = xv[r * 2], b = xv[r * 2 + 1];
#pragma unroll
    for (int h = 0; h < 4; ++h) {
      const float* wp = w + h * 8;
      float s = acc[r][h];
      s = fmaf(a.x, wp[0], s); s = fmaf(a.y, wp[1], s);
      s = fmaf(a.z, wp[2], s); s = fmaf(a.w, wp[3], s);
      s = fmaf(b.x, wp[4], s); s = fmaf(b.y, wp[5], s);
      s = fmaf(b.z, wp[6], s); s = fmaf(b.w, wp[7], s);
      acc[r][h] = s;
    }
  }
}

// ---------------------------------------------------------------------------
// Kernel 1: Whcat = x @ W_heads (4 heads fused per thread), s1/s2 reductions.
// 256 thr / 8 rows / 512 blocks. Wave w: row-group w>>1 (4 rows), k-half w&1.
// Register double-buffer: prefetch next 8-k group (32 W + 8 x) during the
// current group's 128 FMAs -> ~256 cyc latency cover vs ~200 cyc L2.
// ---------------------------------------------------------------------------
__global__ __launch_bounds__(256) void k_wh_heads(
    const float* __restrict__ x, const float* __restrict__ W_heads,
    const float* __restrict__ a_heads, float* __restrict__ Whcat,
    float* __restrict__ s1, float* __restrict__ s2) {
  __shared__ float xs[8][DD];            // 16 KB
  __shared__ float pbuf[2][4][4][64];    // [rowgrp][r][h][f] partials, 8 KB
  int tid = threadIdx.x;
  int r0 = blockIdx.x * 8;
  const float4* xsrc = (const float4*)(x + (size_t)r0 * DD);
  float4* xd = (float4*)xs;
  xd[tid] = xsrc[tid];
  xd[tid + 256] = xsrc[tid + 256];
  xd[tid + 512] = xsrc[tid + 512];
  xd[tid + 768] = xsrc[tid + 768];
  __syncthreads();
  int f = tid & 63;
  int w = tid >> 6;
  int rg = w >> 1;        // row group: rows rg*4 .. rg*4+3
  int kh = w & 1;         // k half
  int k0 = kh * 256;
  const float* Wf = W_heads + f;
  float acc[4][4] = {};   // [r][h]
  float wA[32], wB[32];
  float4 xA[8], xB[8];
  wh_load(Wf, xs, rg, k0, wA, xA);
  for (int k = k0; k < k0 + 256; k += 16) {
    if (k + 8 < k0 + 256) wh_load(Wf, xs, rg, k + 8, wB, xB);
    wh_fma(wA, xA, acc);
    if (k + 16 < k0 + 256) wh_load(Wf, xs, rg, k + 16, wA, xA);
    wh_fma(wB, xB, acc);
  }
  // combine the two k-halves through LDS; even waves (kh==0) finish.
  if (kh == 1) {
#pragma unroll
    for (int r = 0; r < 4; ++r)
#pragma unroll
      for (int h = 0; h < 4; ++h) pbuf[rg][r][h][f] = acc[r][h];
  }
  __syncthreads();
  if (kh == 0) {
#pragma unroll
    for (int r = 0; r < 4; ++r)
#pragma unroll
      for (int h = 0; h < 4; ++h) acc[r][h] += pbuf[rg][r][h][f];
    int rb = r0 + rg * 4;
#pragma unroll
    for (int r = 0; r < 4; ++r)
#pragma unroll
      for (int h = 0; h < 4; ++h)
        Whcat[(size_t)(rb + r) * (NH * F1) + h * 64 + f] = acc[r][h];
#pragma unroll
    for (int h = 0; h < 4; ++h) {
      float a1 = a_heads[h * 2 * F1 + f];
      float a2 = a_heads[h * 2 * F1 + F1 + f];
#pragma unroll
      for (int r = 0; r < 4; ++r) {
        float v1 = acc[r][h] * a1;
        float v2 = acc[r][h] * a2;
#pragma unroll
        for (int off = 32; off > 0; off >>= 1) {
          v1 += __shfl_down(v1, off, 64);
          v2 += __shfl_down(v2, off, 64);
        }
        if (f == 0) {
          s1[h * NN + rb + r] = v1;
          s2[h * NN + rb + r] = v2;
        }
      }
    }
  }
}

// ---------------------------------------------------------------------------
// Kernel 2: multi-head GAT aggregation. Block per row; wave h = head h.
// Weights precomputed in parallel; gather loop unrolled x4 (4 loads in flight).
// ---------------------------------------------------------------------------
__global__ void k_gat_heads(const int* __restrict__ colidx, const int* __restrict__ deg,
                            const float* __restrict__ Whcat,
                            const float* __restrict__ s1, const float* __restrict__ s2,
                            float* __restrict__ cat) {
  __shared__ int idx[CAP];
  __shared__ float wsh[NH][CAP];
  int i = blockIdx.x, tid = threadIdx.x;
  int c = deg[i];
  for (int t = tid; t < c; t += 256) idx[t] = colidx[(size_t)i * CAP + t];
  __syncthreads();
  int h = tid >> 6;
  int f = tid & 63;
  const float* s2h = s2 + h * NN;
  float s1v = s1[h * NN + i];
  float M = -INFINITY;
  for (int k = f; k < c; k += 64) {
    float v = s2h[idx[k]];
    wsh[h][k] = v;
    M = fmaxf(M, v);
  }
#pragma unroll
  for (int off = 32; off > 0; off >>= 1) M = fmaxf(M, __shfl_down(M, off, 64));
  M = __shfl(M, 0, 64);
  float m = lrelu(s1v + M);
  float lsum = 0.f;
  for (int k = f; k < c; k += 64) {
    float w = __expf(lrelu(s1v + wsh[h][k]) - m);
    wsh[h][k] = w;
    lsum += w;
  }
#pragma unroll
  for (int off = 32; off > 0; off >>= 1) lsum += __shfl_down(lsum, off, 64);
  float linv = 1.f / __shfl(lsum, 0, 64);
  __syncthreads();
  const float* base = Whcat + h * 64 + f;
  float a0 = 0.f, a1 = 0.f, a2 = 0.f, a3 = 0.f;
  int k = 0;
  for (; k + 4 <= c; k += 4) {
    int j0 = idx[k], j1 = idx[k + 1], j2 = idx[k + 2], j3 = idx[k + 3];
    a0 = fmaf(wsh[h][k],     base[(size_t)j0 * 256], a0);
    a1 = fmaf(wsh[h][k + 1], base[(size_t)j1 * 256], a1);
    a2 = fmaf(wsh[h][k + 2], base[(size_t)j2 * 256], a2);
    a3 = fmaf(wsh[h][k + 3], base[(size_t)j3 * 256], a3);
  }
  for (; k < c; ++k) a0 = fmaf(wsh[h][k], base[(size_t)idx[k] * 256], a0);
  float o = (a0 + a1 + a2 + a3) * linv;
  cat[(size_t)i * (NH * F1) + tid] = (o > 0.f) ? o : expm1f(o);
}

// ---------------------------------------------------------------------------
// Kernel 3: Wh2 = cat @ W_att  [NN,256]x[256,64], plus s1b/s2b reductions
// ---------------------------------------------------------------------------
__global__ void k_wh2(const float* __restrict__ cat,
                      const float* __restrict__ W_att,
                      const float* __restrict__ a_att,
                      float* __restrict__ Wh2,
                      float* __restrict__ s1b, float* __restrict__ s2b) {
  const int ROWS = 8;
  __shared__ float cs[ROWS][NH * F1];
  int tid = threadIdx.x;
  int r0 = blockIdx.x * ROWS;
  const float4* csrc = (const float4*)(cat + (size_t)r0 * 256);
  for (int t = tid; t < ROWS * 256 / 4; t += 256) ((float4*)cs)[t] = csrc[t];
  __syncthreads();
  int g = tid >> 6;
  int f = tid & 63;
  float a1 = a_att[f], a2 = a_att[64 + f];
  const float* W = W_att + f;
#pragma unroll
  for (int rr = 0; rr < 2; ++rr) {
    int r = g * 2 + rr;
    float acc = 0.f;
    for (int k = 0; k < 256; k += 4) {
      float4 cv = *(const float4*)&cs[r][k];
      acc = fmaf(cv.x, W[(k + 0) * 64], acc);
      acc = fmaf(cv.y, W[(k + 1) * 64], acc);
      acc = fmaf(cv.z, W[(k + 2) * 64], acc);
      acc = fmaf(cv.w, W[(k + 3) * 64], acc);
    }
    Wh2[(size_t)(r0 + r) * 64 + f] = acc;
    float v1 = acc * a1, v2 = acc * a2;
#pragma unroll
    for (int off = 32; off > 0; off >>= 1) {
      v1 += __shfl_down(v1, off, 64);
      v2 += __shfl_down(v2, off, 64);
    }
    if (f == 0) { s1b[r0 + r] = v1; s2b[r0 + r] = v2; }
  }
}

// ---------------------------------------------------------------------------
// Kernel 4: single-head GAT + fused t1 = gc @ W1. 4 rows/block, wave per row.
// gc never hits HBM.
// ---------------------------------------------------------------------------
__global__ void k_gat2t1(const int* __restrict__ colidx, const int* __restrict__ deg,
                         const float* __restrict__ Wh2,
                         const float* __restrict__ s1b, const float* __restrict__ s2b,
                         const float* __restrict__ W1, float* __restrict__ t1) {
  __shared__ int idx4[4][CAP];
  __shared__ float wsh4[4][CAP];
  __shared__ float grow[4][64];
  __shared__ float W1s[F1 * F2];  // 8 KB
  int tid = threadIdx.x;
  int w = tid >> 6, f = tid & 63;
  int i = blockIdx.x * 4 + w;
  int c = deg[i];
  for (int t = tid; t < F1 * F2; t += 256) W1s[t] = W1[t];
  for (int k = f; k < c; k += 64) idx4[w][k] = colidx[(size_t)i * CAP + k];
  __syncthreads();
  float s1v = s1b[i];
  float M = -INFINITY;
  for (int k = f; k < c; k += 64) {
    float v = s2b[idx4[w][k]];
    wsh4[w][k] = v;
    M = fmaxf(M, v);
  }
#pragma unroll
  for (int off = 32; off > 0; off >>= 1) M = fmaxf(M, __shfl_down(M, off, 64));
  M = __shfl(M, 0, 64);
  float m = lrelu(s1v + M);
  float lsum = 0.f;
  for (int k = f; k < c; k += 64) {
    float wv = __expf(lrelu(s1v + wsh4[w][k]) - m);
    wsh4[w][k] = wv;
    lsum += wv;
  }
#pragma unroll
  for (int off = 32; off > 0; off >>= 1) lsum += __shfl_down(lsum, off, 64);
  float linv = 1.f / __shfl(lsum, 0, 64);
  __syncthreads();
  const float* base = Wh2 + f;
  float a0 = 0.f, a1 = 0.f, a2 = 0.f, a3 = 0.f;
  int k = 0;
  for (; k + 4 <= c; k += 4) {
    int j0 = idx4[w][k], j1 = idx4[w][k + 1], j2 = idx4[w][k + 2], j3 = idx4[w][k + 3];
    a0 = fmaf(wsh4[w][k],     base[(size_t)j0 * 64], a0);
    a1 = fmaf(wsh4[w][k + 1], base[(size_t)j1 * 64], a1);
    a2 = fmaf(wsh4[w][k + 2], base[(size_t)j2 * 64], a2);
    a3 = fmaf(wsh4[w][k + 3], base[(size_t)j3 * 64], a3);
  }
  for (; k < c; ++k) a0 = fmaf(wsh4[w][k], base[(size_t)idx4[w][k] * 64], a0);
  float o = (a0 + a1 + a2 + a3) * linv;
  grow[w][f] = (o > 0.f) ? o : expm1f(o);
  __syncthreads();
  if (f < F2) {
    float acc = 0.f;
#pragma unroll 8
    for (int kk = 0; kk < F1; ++kk) acc = fmaf(grow[w][kk], W1s[kk * F2 + f], acc);
    t1[(size_t)i * F2 + f] = acc;
  }
}

// ---------------------------------------------------------------------------
// Kernel 5: h1 = relu(adj @ t1) fused with t23 = h1 @ [W2|W3].
// 4 rows/block, wave per row, 2 neighbors per iter (64 lanes = 2 x 32 feats).
// h1 never hits HBM.
// ---------------------------------------------------------------------------
__global__ void k_gcn1t23(const int* __restrict__ colidx, const int* __restrict__ deg,
                          const float* __restrict__ t1,
                          const float* __restrict__ W2, const float* __restrict__ W3,
                          float* __restrict__ t23) {
  __shared__ int idx4[4][CAP];
  __shared__ float hrow[4][F2];
  __shared__ float Wc[F2 * 32];  // [k][g]: g<16 -> W2, g>=16 -> W3
  int tid = threadIdx.x;
  int w = tid >> 6, lane = tid & 63;
  int nb = lane >> 5, g = lane & 31;
  int i = blockIdx.x * 4 + w;
  int c = deg[i];
  for (int t = tid; t < F2 * 32; t += 256) {
    int kk = t >> 5, gg = t & 31;
    Wc[t] = (gg < 16) ? W2[kk * 16 + gg] : W3[kk * 16 + (gg - 16)];
  }
  for (int k = lane; k < c; k += 64) idx4[w][k] = colidx[(size_t)i * CAP + k];
  __syncthreads();
  float a0 = 0.f, a1 = 0.f;
  int k = nb;
  for (; k + 2 < c; k += 4) {
    a0 += t1[(size_t)idx4[w][k] * F2 + g];
    a1 += t1[(size_t)idx4[w][k + 2] * F2 + g];
  }
  for (; k < c; k += 2) a0 += t1[(size_t)idx4[w][k] * F2 + g];
  float tot = a0 + a1;
  tot += __shfl_xor(tot, 32, 64);
  float h1v = fmaxf(tot, 0.f);
  if (nb == 0) hrow[w][g] = h1v;
  __syncthreads();
  if (lane < 32) {
    float acc = 0.f;
#pragma unroll 8
    for (int kk = 0; kk < F2; ++kk) acc = fmaf(hrow[w][kk], Wc[kk * 32 + lane], acc);
    t23[(size_t)i * 32 + lane] = acc;
  }
}

// ---------------------------------------------------------------------------
// Kernel 6: mu/logvar = adj @ t23 ; z = eps*exp(logvar)+mu. Wave per row.
// ---------------------------------------------------------------------------
__global__ void k_gcn2(const int* __restrict__ colidx, const int* __restrict__ deg,
                       const float* __restrict__ t23, const float* __restrict__ eps,
                       float* __restrict__ mu_out, float* __restrict__ lv_out,
                       float* __restrict__ z) {
  __shared__ int idx4[4][CAP];
  int tid = threadIdx.x;
  int w = tid >> 6, lane = tid & 63;
  int nb = lane >> 5, g = lane & 31;
  int i = blockIdx.x * 4 + w;
  int c = deg[i];
  for (int k = lane; k < c; k += 64) idx4[w][k] = colidx[(size_t)i * CAP + k];
  __syncthreads();
  float a0 = 0.f, a1 = 0.f;
  int k = nb;
  for (; k + 2 < c; k += 4) {
    a0 += t23[(size_t)idx4[w][k] * 32 + g];
    a1 += t23[(size_t)idx4[w][k + 2] * 32 + g];
  }
  for (; k < c; k += 2) a0 += t23[(size_t)idx4[w][k] * 32 + g];
  float tot = a0 + a1;
  tot += __shfl_xor(tot, 32, 64);
  // lanes 0..31 hold [mu(0..15) | lv(16..31)]
  float lvv = __shfl(tot, (lane & 31) + 16, 64);  // valid for g<16
  if (lane < 16) {
    mu_out[(size_t)i * 16 + g] = tot;
    z[(size_t)i * 16 + g] = eps[(size_t)i * 16 + g] * expf(lvv) + tot;
  } else if (lane < 32) {
    lv_out[(size_t)i * 16 + (g - 16)] = tot;
  }
}

// ---------------------------------------------------------------------------
// Kernel 7: adj_rec = z @ z^T. 64x64 tiles, rank-16, float4 stores.
// ---------------------------------------------------------------------------
__global__ void k_zzt(const float* __restrict__ z, float* __restrict__ out) {
  __shared__ float zr[64][17];
  __shared__ float zc[64][17];
  int bj = blockIdx.x, bi = blockIdx.y;
  int tid = threadIdx.x;
  for (int t = tid; t < 64 * 16; t += 256) {
    int r = t >> 4, kk = t & 15;
    zr[r][kk] = z[(size_t)(bi * 64 + r) * 16 + kk];
    zc[r][kk] = z[(size_t)(bj * 64 + r) * 16 + kk];
  }
  __syncthreads();
  int rg = tid >> 4;        // 16 row groups x 4 rows
  int cg = tid & 15;        // 16 col groups x 4 cols
  float acc[4][4] = {};
  for (int kk = 0; kk < 16; ++kk) {
    float av[4], bv[4];
#pragma unroll
    for (int t = 0; t < 4; ++t) av[t] = zr[rg * 4 + t][kk];
#pragma unroll
    for (int t = 0; t < 4; ++t) bv[t] = zc[cg * 4 + t][kk];
#pragma unroll
    for (int r = 0; r < 4; ++r)
#pragma unroll
      for (int cc = 0; cc < 4; ++cc) acc[r][cc] = fmaf(av[r], bv[cc], acc[r][cc]);
  }
#pragma unroll
  for (int r = 0; r < 4; ++r) {
    float4 v = make_float4(acc[r][0], acc[r][1], acc[r][2], acc[r][3]);
    *(float4*)&out[(size_t)(bi * 64 + rg * 4 + r) * NN + bj * 64 + cg * 4] = v;
  }
}

extern "C" void kernel_launch(void* const* d_in, const int* in_sizes, int n_in,
                              void* d_out, int out_size, void* d_ws, size_t ws_size,
                              hipStream_t stream) {
  const float* x       = (const float*)d_in[0];
  const float* adj     = (const float*)d_in[1];
  const float* W_heads = (const float*)d_in[2];
  const float* a_heads = (const float*)d_in[3];
  const float* W_att   = (const float*)d_in[4];
  const float* a_att   = (const float*)d_in[5];
  const float* W1      = (const float*)d_in[6];
  const float* W2      = (const float*)d_in[7];
  const float* W3      = (const float*)d_in[8];
  const float* eps     = (const float*)d_in[9];

  float* out = (float*)d_out;
  float* adj_rec = out;
  float* mu_out  = out + (size_t)NN * NN;
  float* lv_out  = mu_out + (size_t)NN * F3;

  float* ws = (float*)d_ws;
  float* Whcat = ws;               ws += (size_t)NN * NH * F1;
  float* s1    = ws;               ws += (size_t)NH * NN;
  float* s2    = ws;               ws += (size_t)NH * NN;
  float* cat   = ws;               ws += (size_t)NN * NH * F1;
  float* Wh2   = ws;               ws += (size_t)NN * F1;
  float* s1b   = ws;               ws += NN;
  float* s2b   = ws;               ws += NN;
  float* t1    = ws;               ws += (size_t)NN * F2;
  float* t23   = ws;               ws += (size_t)NN * 2 * F3;
  float* z     = ws;               ws += (size_t)NN * F3;
  int*   colidx = (int*)ws;        ws += (size_t)NN * CAP;
  int*   deg    = (int*)ws;        ws += NN;

  k_csr<<<NN, 256, 0, stream>>>(adj, colidx, deg);
  k_wh_heads<<<NN / 8, 256, 0, stream>>>(x, W_heads, a_heads, Whcat, s1, s2);
  k_gat_heads<<<NN, 256, 0, stream>>>(colidx, deg, Whcat, s1, s2, cat);
  k_wh2<<<NN / 8, 256, 0, stream>>>(cat, W_att, a_att, Wh2, s1b, s2b);
  k_gat2t1<<<NN / 4, 256, 0, stream>>>(colidx, deg, Wh2, s1b, s2b, W1, t1);
  k_gcn1t23<<<NN / 4, 256, 0, stream>>>(colidx, deg, t1, W2, W3, t23);
  k_gcn2<<<NN / 4, 256, 0, stream>>>(colidx, deg, t23, eps, mu_out, lv_out, z);
  k_zzt<<<dim3(64, 64), 256, 0, stream>>>(z, adj_rec);
}